// Round 1
// baseline (714.502 us; speedup 1.0000x reference)
//
#include <hip/hip_runtime.h>
#include <stdint.h>

// Problem constants (QSGDLinear): out = x @ W^T
//   x: (2,1024,4096) fp32 -> M=2048, K=4096
//   ternary: (16384,4096) int32 in {-1,0,1} -> N=16384
//   scales: (16384*4096/128,) fp32, group = contiguous 128 along K of one row
#define M_ROWS 2048
#define IN_F   4096
#define OUT_F  16384

#define BM 256
#define BN 256
#define BK 64
#define NT (IN_F / BK)   // 64 k-tiles

typedef __attribute__((ext_vector_type(8))) short short8;   // 8 bf16 = 4 VGPRs
typedef __attribute__((ext_vector_type(4))) float floatx4;  // MFMA acc

#define FENCE() __asm__ __volatile__("" ::: "memory")
#define BAR()   do { FENCE(); __builtin_amdgcn_s_barrier(); FENCE(); } while (0)

__device__ __forceinline__ unsigned short f32_to_bf16_rne(float f) {
    union { float f; uint32_t u; } v; v.f = f;
    uint32_t u = v.u;
    return (unsigned short)((u + 0x7FFFu + ((u >> 16) & 1u)) >> 16);
}

// ---- pass 1: x fp32 -> bf16 (8 elems/thread) ----
__global__ __launch_bounds__(256) void convert_x_kernel(
        const float* __restrict__ x, unsigned short* __restrict__ xb) {
    int t = blockIdx.x * 256 + threadIdx.x;
    const float4* p = (const float4*)(x + (size_t)t * 8);
    float4 a = p[0];
    float4 b = p[1];
    short8 o;
    o[0] = (short)f32_to_bf16_rne(a.x);
    o[1] = (short)f32_to_bf16_rne(a.y);
    o[2] = (short)f32_to_bf16_rne(a.z);
    o[3] = (short)f32_to_bf16_rne(a.w);
    o[4] = (short)f32_to_bf16_rne(b.x);
    o[5] = (short)f32_to_bf16_rne(b.y);
    o[6] = (short)f32_to_bf16_rne(b.z);
    o[7] = (short)f32_to_bf16_rne(b.w);
    *(short8*)(xb + (size_t)t * 8) = o;
}

// ---- pass 2: W = ternary * scale -> bf16 (8 elems/thread, all same group) ----
__global__ __launch_bounds__(256) void dequant_w_kernel(
        const int* __restrict__ tern, const float* __restrict__ scales,
        unsigned short* __restrict__ wb) {
    int g = blockIdx.x * 256 + threadIdx.x;          // 8 elems per thread
    float s = scales[g >> 4];                        // (g*8)/128
    const int4* p = (const int4*)(tern + (size_t)g * 8);
    int4 a = p[0];
    int4 b = p[1];
    short8 o;
    o[0] = (short)f32_to_bf16_rne((float)a.x * s);
    o[1] = (short)f32_to_bf16_rne((float)a.y * s);
    o[2] = (short)f32_to_bf16_rne((float)a.z * s);
    o[3] = (short)f32_to_bf16_rne((float)a.w * s);
    o[4] = (short)f32_to_bf16_rne((float)b.x * s);
    o[5] = (short)f32_to_bf16_rne((float)b.y * s);
    o[6] = (short)f32_to_bf16_rne((float)b.z * s);
    o[7] = (short)f32_to_bf16_rne((float)b.w * s);
    *(short8*)(wb + (size_t)g * 8) = o;
}

// ---- pass 3: C = A * B^T, 256x256 tile, 8-wave, counted-vmcnt phase schedule ----
//
// Tiles: BMxBN=256x256, BK=64 split into two K-halves of 32. Stage unit =
// one half (256 rows x 32 k = 16 KB = 2 global_load_lds x 16B per thread).
// Per tile, 4 phases; phase p: { stage one half of tile t+1 (into buf^1) ;
// s_waitcnt vmcnt(6) ; s_barrier ; ds_read frags ; 16 MFMA }.
// Stage order A0,B0,A1,B1; first-use gaps are 4,3,4,3 stage-slots, so
// vmcnt(6) (= 3 stages in flight) at every phase guarantees residency.
// Stages always target the non-read buffer -> 1 barrier/phase is race-free.
//
// LDS half layout: 128-B line L holds rows {2L,2L+1}; 16B slot within line
// s8 = ((r&1)*4 + kchunk) ^ (L&7). Frag ds_read_b128: per 16-lane group the
// 16 (line,slot) targets hit all 8 bank-quads exactly 2x -> 2-way (free).
// gload_lds dest is lane-linear; the swizzle lives in the global src addr.
__device__ __forceinline__ floatx4 mfma16(short8 a, short8 b, floatx4 c) {
    return __builtin_amdgcn_mfma_f32_16x16x32_bf16(a, b, c, 0, 0, 0);
}

__device__ __forceinline__ void stage_half(
        const unsigned short* G, unsigned short* Ld,
        int row0, int kofs, const int* srow, const int* scol, const int* sub) {
#pragma unroll
    for (int i = 0; i < 2; ++i) {
        const unsigned short* gsrc =
            G + (size_t)(row0 + srow[i]) * IN_F + kofs + scol[i];
        __builtin_amdgcn_global_load_lds(
            (const __attribute__((address_space(1))) void*)gsrc,
            (__attribute__((address_space(3))) void*)(Ld + sub[i]), 16, 0, 0);
    }
}

#define READ_AF(base) \
    _Pragma("unroll") \
    for (int t2 = 0; t2 < 8; ++t2) af[t2] = *(const short8*)((base) + a_off[t2]);

#define MFMA16x2(BF, n0, n1) \
    _Pragma("unroll") \
    for (int t2 = 0; t2 < 8; ++t2) { \
        acc[t2][n0] = mfma16(af[t2], (BF)[0], acc[t2][n0]); \
        acc[t2][n1] = mfma16(af[t2], (BF)[1], acc[t2][n1]); \
    }

__global__ __launch_bounds__(512, 2) void gemm_bt_kernel(
        const unsigned short* __restrict__ A,   // [M_ROWS][IN_F] bf16 bits
        const unsigned short* __restrict__ B,   // [OUT_F][IN_F] bf16 bits
        float* __restrict__ C) {                // [M_ROWS][OUT_F] fp32
    __shared__ unsigned short As[2][2][8192];   // [buf][k-half][256r x 32k] 64 KB
    __shared__ unsigned short Bs[2][2][8192];   // 64 KB

    const int tid  = threadIdx.x;
    const int lane = tid & 63;
    const int quad = lane >> 4;        // k-chunk within half (0..3)
    const int frow = lane & 15;
    const int w    = tid >> 6;         // wave 0..7
    const int wr   = w >> 2;           // 0..1 -> 128 rows each
    const int wc   = w & 3;            // 0..3 -> 64 cols each

    // XCD-bijective swizzle (512 blocks % 8 XCDs == 0): each XCD owns an
    // 8(m) x 8(n) supertile -> B panels fetched once, shared in its L2.
    const int bid = blockIdx.x;
    const int swz = (bid & 7) * 64 + (bid >> 3);
    const int bm  = (swz & 7) * BM;    // 8 m-tiles
    const int bn  = (swz >> 3) * BN;   // 64 n-tiles

    // fragment LDS element-offsets within a half (same for both halves)
    int a_off[8], b_off[4];
#pragma unroll
    for (int t2 = 0; t2 < 8; ++t2) {
        int r = wr * 128 + t2 * 16 + frow;
        a_off[t2] = (r >> 1) * 64 +
                    (((((r & 1) << 2) + quad) ^ ((r >> 1) & 7)) << 3);
    }
#pragma unroll
    for (int nf = 0; nf < 4; ++nf) {
        int r = wc * 64 + nf * 16 + frow;
        b_off[nf] = (r >> 1) * 64 +
                    (((((r & 1) << 2) + quad) ^ ((r >> 1) & 7)) << 3);
    }

    // staging addresses: chunk cid = i*512+tid -> line=cid>>3, k8=(cid&7)^(line&7)
    // -> global row = 2*line + (k8>>2), k-chunk = k8&3. LDS dest linear in cid.
    int srow[2], scol[2], sub[2];
#pragma unroll
    for (int i = 0; i < 2; ++i) {
        int cid = i * 512 + tid;
        int ln  = cid >> 3;
        int k8  = (cid & 7) ^ (ln & 7);
        srow[i] = 2 * ln + (k8 >> 2);
        scol[i] = (k8 & 3) * 8;
        sub[i]  = (i * 512 + (tid & 448)) * 8;   // wave-uniform LDS base (elems)
    }

    floatx4 acc[8][4] = {};
    short8 af[8], bfA[2], bfB[2];

    // prologue: stage tile 0 fully -> 8 loads/thread in flight
    stage_half(A, &As[0][0][0], bm, 0,  srow, scol, sub);
    stage_half(B, &Bs[0][0][0], bn, 0,  srow, scol, sub);
    stage_half(A, &As[0][1][0], bm, 32, srow, scol, sub);
    stage_half(B, &Bs[0][1][0], bn, 32, srow, scol, sub);

#pragma unroll 1
    for (int t = 0; t < NT - 1; ++t) {
        const int buf = t & 1, nbuf = buf ^ 1;
        const int ktn = (t + 1) * BK;
        const unsigned short* a0 = &As[buf][0][0];
        const unsigned short* a1 = &As[buf][1][0];
        const unsigned short* b0 = &Bs[buf][0][0];
        const unsigned short* b1 = &Bs[buf][1][0];

        // ---- phase 0: prefetch next A0; compute k-half0 x nf{0,1}
        stage_half(A, &As[nbuf][0][0], bm, ktn, srow, scol, sub);
        __asm__ __volatile__("s_waitcnt vmcnt(6)" ::: "memory");
        BAR();
        READ_AF(a0);
        bfA[0] = *(const short8*)(b0 + b_off[0]);
        bfA[1] = *(const short8*)(b0 + b_off[1]);
        __builtin_amdgcn_s_setprio(1);
        MFMA16x2(bfA, 0, 1);
        __builtin_amdgcn_s_setprio(0);

        // ---- phase 1: prefetch next B0; compute k-half0 x nf{2,3}
        stage_half(B, &Bs[nbuf][0][0], bn, ktn, srow, scol, sub);
        __asm__ __volatile__("s_waitcnt vmcnt(6)" ::: "memory");
        BAR();
        bfB[0] = *(const short8*)(b0 + b_off[2]);
        bfB[1] = *(const short8*)(b0 + b_off[3]);
        __builtin_amdgcn_s_setprio(1);
        MFMA16x2(bfB, 2, 3);
        __builtin_amdgcn_s_setprio(0);

        // ---- phase 2: prefetch next A1; compute k-half1 x nf{0,1}
        stage_half(A, &As[nbuf][1][0], bm, ktn + 32, srow, scol, sub);
        __asm__ __volatile__("s_waitcnt vmcnt(6)" ::: "memory");
        BAR();
        READ_AF(a1);
        bfA[0] = *(const short8*)(b1 + b_off[0]);
        bfA[1] = *(const short8*)(b1 + b_off[1]);
        __builtin_amdgcn_s_setprio(1);
        MFMA16x2(bfA, 0, 1);
        __builtin_amdgcn_s_setprio(0);

        // ---- phase 3: prefetch next B1; compute k-half1 x nf{2,3}
        stage_half(B, &Bs[nbuf][1][0], bn, ktn + 32, srow, scol, sub);
        __asm__ __volatile__("s_waitcnt vmcnt(6)" ::: "memory");
        BAR();
        bfB[0] = *(const short8*)(b1 + b_off[2]);
        bfB[1] = *(const short8*)(b1 + b_off[3]);
        __builtin_amdgcn_s_setprio(1);
        MFMA16x2(bfB, 2, 3);
        __builtin_amdgcn_s_setprio(0);
    }

    // ---- peeled last tile: drain 4 -> 0 (no more stages)
    {
        const unsigned short* a0 = &As[(NT - 1) & 1][0][0];
        const unsigned short* a1 = &As[(NT - 1) & 1][1][0];
        const unsigned short* b0 = &Bs[(NT - 1) & 1][0][0];
        const unsigned short* b1 = &Bs[(NT - 1) & 1][1][0];

        __asm__ __volatile__("s_waitcnt vmcnt(4)" ::: "memory");  // B0 landed
        BAR();
        READ_AF(a0);
        bfA[0] = *(const short8*)(b0 + b_off[0]);
        bfA[1] = *(const short8*)(b0 + b_off[1]);
        bfB[0] = *(const short8*)(b0 + b_off[2]);
        bfB[1] = *(const short8*)(b0 + b_off[3]);
        __builtin_amdgcn_s_setprio(1);
        MFMA16x2(bfA, 0, 1);
        MFMA16x2(bfB, 2, 3);
        __builtin_amdgcn_s_setprio(0);

        __asm__ __volatile__("s_waitcnt vmcnt(0)" ::: "memory");  // A1,B1 landed
        BAR();
        READ_AF(a1);
        bfA[0] = *(const short8*)(b1 + b_off[0]);
        bfA[1] = *(const short8*)(b1 + b_off[1]);
        bfB[0] = *(const short8*)(b1 + b_off[2]);
        bfB[1] = *(const short8*)(b1 + b_off[3]);
        __builtin_amdgcn_s_setprio(1);
        MFMA16x2(bfA, 0, 1);
        MFMA16x2(bfB, 2, 3);
        __builtin_amdgcn_s_setprio(0);
    }

    // epilogue: C/D layout col = lane&15, row = quad*4 + reg  [m89/m91]
    const int row0 = bm + wr * 128 + quad * 4;
    const int col0 = bn + wc * 64 + frow;
#pragma unroll
    for (int t2 = 0; t2 < 8; ++t2) {
#pragma unroll
        for (int nf = 0; nf < 4; ++nf) {
            float* cp = C + (size_t)(row0 + t2 * 16) * OUT_F + (col0 + nf * 16);
#pragma unroll
            for (int r = 0; r < 4; ++r)
                cp[(size_t)r * OUT_F] = acc[t2][nf][r];
        }
    }
}

extern "C" void kernel_launch(void* const* d_in, const int* in_sizes, int n_in,
                              void* d_out, int out_size, void* d_ws, size_t ws_size,
                              hipStream_t stream) {
    const float* x     = (const float*)d_in[0];
    const int*   tern  = (const int*)d_in[1];
    const float* scal  = (const float*)d_in[2];
    float*       out   = (float*)d_out;

    // workspace: x_bf16 (16 MB) then w_bf16 (128 MB)
    unsigned short* xb = (unsigned short*)d_ws;
    unsigned short* wb = xb + (size_t)M_ROWS * IN_F;

    convert_x_kernel<<<(M_ROWS * IN_F / 8) / 256, 256, 0, stream>>>(x, xb);
    dequant_w_kernel<<<((size_t)OUT_F * IN_F / 8) / 256, 256, 0, stream>>>(tern, scal, wb);
    gemm_bt_kernel<<<dim3((M_ROWS / BM) * (OUT_F / BN)), 512, 0, stream>>>(xb, wb, out);
}